// Round 3
// baseline (2396.434 us; speedup 1.0000x reference)
//
#include <hip/hip_runtime.h>
#include <hip/hip_bf16.h>

#define B_ 16
#define N_ 1024
#define C_ 768
#define H_ 12
#define HD_ 64
#define QC_ (3*C_)      // 2304

using bf16 = __hip_bfloat16;

__device__ __forceinline__ float tof(bf16 v){ return __bfloat162float(v); }
__device__ __forceinline__ float bflo(unsigned u){ return __uint_as_float(u << 16); }
__device__ __forceinline__ float bfhi(unsigned u){ return __uint_as_float(u & 0xffff0000u); }

// ---------------------------------------------------------------------------
// Input-dtype detector: bits 14:7 of sampled u32 words of x are a bf16
// exponent field (clustered ~[110,140]) if x is packed bf16, uniform random
// mantissa bits if x is fp32. Writes 1=bf16 / 0=fp32 to *flag.
// ---------------------------------------------------------------------------
__global__ __launch_bounds__(256) void detect_dtype(
    const unsigned* __restrict__ x32, int* __restrict__ flag)
{
  __shared__ int cnt;
  if (threadIdx.x == 0) cnt = 0;
  __syncthreads();
  int local = 0;
  #pragma unroll
  for (int i = 0; i < 16; i++) {
    unsigned u = x32[threadIdx.x * 16 + i * 4096];   // max idx 65520 < 6.29M
    unsigned e = (u >> 7) & 0xFF;
    local += (e >= 110 && e <= 140) ? 1 : 0;
  }
  atomicAdd(&cnt, local);
  __syncthreads();
  if (threadIdx.x == 0) *flag = (cnt > 2048) ? 1 : 0;
}

// ---------------------------------------------------------------------------
// GEMM: Cout[(row_off+0..Mt) x Nd] = A[(row_off+r) x K] * W[K x Nd] + bias.
// fp32 accumulate. Operand dtype modes: 0=fp32, 1=bf16, 2=follow *flag.
// 128x128 tile, K-step 16, 8x8 per thread, 256 threads.
// ---------------------------------------------------------------------------
__device__ __forceinline__ void load8(const void* base, size_t eoff, bool isbf,
                                      float f[8])
{
  if (isbf) {
    uint4 v = *(const uint4*)((const bf16*)base + eoff);
    f[0]=bflo(v.x); f[1]=bfhi(v.x); f[2]=bflo(v.y); f[3]=bfhi(v.y);
    f[4]=bflo(v.z); f[5]=bfhi(v.z); f[6]=bflo(v.w); f[7]=bfhi(v.w);
  } else {
    const float4* p = (const float4*)((const float*)base + eoff);
    float4 a = p[0], b = p[1];
    f[0]=a.x; f[1]=a.y; f[2]=a.z; f[3]=a.w;
    f[4]=b.x; f[5]=b.y; f[6]=b.z; f[7]=b.w;
  }
}

__global__ __launch_bounds__(256) void gemm_bias_128(
    const void* __restrict__ A, const void* __restrict__ W,
    const void* __restrict__ bias, void* __restrict__ Cout,
    const int Nd, const int K, const int a_row_off, const int c_row_off,
    const int* __restrict__ flag,
    const int a_mode, const int w_mode, const int c_mode)
{
  const int fl = *flag;
  const bool abf = (a_mode == 2) ? (fl != 0) : (a_mode != 0);
  const bool wbf = (w_mode == 2) ? (fl != 0) : (w_mode != 0);
  const bool cbf = (c_mode == 2) ? (fl != 0) : (c_mode != 0);

  __shared__ float As[16][132];   // [k][m]
  __shared__ float Bs[16][132];   // [k][n]
  const int tid  = threadIdx.x;
  const int tx   = tid & 15;
  const int ty   = tid >> 4;
  const int row0 = blockIdx.x * 128;
  const int col0 = blockIdx.y * 128;

  const int ar = tid >> 1;          // 0..127
  const int ak = (tid & 1) << 3;    // 0 or 8
  const int bk = tid >> 4;          // 0..15
  const int bc = (tid & 15) << 3;   // 0..120

  float acc[8][8];
  #pragma unroll
  for (int i=0;i<8;i++)
    #pragma unroll
    for (int j=0;j<8;j++) acc[i][j] = 0.f;

  for (int k0 = 0; k0 < K; k0 += 16) {
    float fa[8], fb[8];
    load8(A, (size_t)(a_row_off + row0 + ar) * K + (k0 + ak), abf, fa);
    load8(W, (size_t)(k0 + bk) * Nd + (col0 + bc), wbf, fb);
    #pragma unroll
    for (int e=0;e<8;e++) As[ak+e][ar] = fa[e];
    *(float4*)&Bs[bk][bc]   = make_float4(fb[0],fb[1],fb[2],fb[3]);
    *(float4*)&Bs[bk][bc+4] = make_float4(fb[4],fb[5],fb[6],fb[7]);
    __syncthreads();
    #pragma unroll
    for (int kk=0;kk<16;kk++){
      float a[8], b[8];
      *(float4*)&a[0] = *(const float4*)&As[kk][ty*8];
      *(float4*)&a[4] = *(const float4*)&As[kk][ty*8+4];
      *(float4*)&b[0] = *(const float4*)&Bs[kk][tx*8];
      *(float4*)&b[4] = *(const float4*)&Bs[kk][tx*8+4];
      #pragma unroll
      for (int i=0;i<8;i++)
        #pragma unroll
        for (int j=0;j<8;j++) acc[i][j] = fmaf(a[i], b[j], acc[i][j]);
    }
    __syncthreads();
  }
  #pragma unroll
  for (int i=0;i<8;i++){
    const size_t r = (size_t)(c_row_off + row0 + ty*8 + i);
    #pragma unroll
    for (int j=0;j<8;j++){
      const int c = col0 + tx*8 + j;
      const float bv = wbf ? tof(((const bf16*)bias)[c]) : ((const float*)bias)[c];
      const float v = acc[i][j] + bv;
      if (cbf) ((bf16*)Cout)[r*Nd + c] = __float2bfloat16(v);
      else     ((float*)Cout)[r*Nd + c] = v;
    }
  }
}

// ---------------------------------------------------------------------------
// RoPE in-place on qkv[M][2304] (always bf16 — our buffer).
// ---------------------------------------------------------------------------
__global__ __launch_bounds__(256) void rope_kernel(
    bf16* __restrict__ qkv, const int* __restrict__ pos_h,
    const int* __restrict__ pos_w, const int M)
{
  const int p = blockIdx.x * 256 + threadIdx.x;     // < M*768
  if (p >= M * 768) return;
  const int bn   = p / 768;
  const int rem  = p - bn * 768;
  const int t    = rem / 384;         // 0=q, 1=k
  const int rem2 = rem - t * 384;
  const int h    = rem2 >> 5;         // head
  const int pj   = rem2 & 31;         // pair index within head
  const int half = pj >> 4;           // 0: pos_h, 1: pos_w
  const int j    = pj & 15;           // partner at +16
  const int fi   = j >> 1;            // frequency index

  const float pos = (float)((half == 0) ? pos_h[bn] : pos_w[bn]);
  const float LOG2_BASE = 13.287712379549449f;     // log2(10000)
  const float f1 = exp2f(-LOG2_BASE * (float)fi        * (1.0f/16.0f));
  const float f2 = exp2f(-LOG2_BASE * (float)(fi + 8)  * (1.0f/16.0f));
  float s1, c1, s2, c2;
  sincosf(pos * f1, &s1, &c1);
  sincosf(pos * f2, &s2, &c2);

  const size_t base = (size_t)bn * QC_ + t * C_ + h * HD_ + half * 32 + j;
  const float v1 = tof(qkv[base]);
  const float v2 = tof(qkv[base + 16]);
  qkv[base]      = __float2bfloat16(v1 * c1 - v2 * s1);
  qkv[base + 16] = __float2bfloat16(v2 * c2 + v1 * s2);
}

// ---------------------------------------------------------------------------
// Flash attention (qkv/ao always bf16). 53 KB LDS: St aliases Ks.
// ---------------------------------------------------------------------------
__global__ __launch_bounds__(256) void attn_kernel(
    const bf16* __restrict__ qkv, bf16* __restrict__ attn_out)
{
  __shared__ float Qs[64][68];    // [d][q-row], scaled by 1/8
  __shared__ float KSs[64][68];   // phase 1: K [d][k-row]; phase 2: St [k][q]
  __shared__ float Vs[64][68];    // [k-row][d]
  __shared__ float m_s[64], l_s[64], a_s[64];
  const int tid = threadIdx.x;
  const int tx  = tid & 15;
  const int ty  = tid >> 4;
  const int qt  = blockIdx.x;            // 0..15
  const int bh  = blockIdx.y;            // local_b*H + h
  const int b   = bh / H_;
  const int h   = bh - b * H_;

  #pragma unroll
  for (int i=0;i<16;i++){
    int idx = tid + (i<<8);
    int r = idx >> 6, d = idx & 63;
    Qs[d][r] = 0.125f * tof(qkv[((size_t)(b*N_ + (qt<<6) + r))*QC_ + h*HD_ + d]);
  }
  if (tid < 64){ m_s[tid] = -3.0e38f; l_s[tid] = 0.f; }
  float o[4][4] = {};

  for (int kt=0; kt<16; kt++){
    __syncthreads();                       // prev iter done with KSs/Vs
    #pragma unroll
    for (int i=0;i<16;i++){
      int idx = tid + (i<<8);
      int r = idx >> 6, d = idx & 63;
      size_t base = ((size_t)(b*N_ + (kt<<6) + r))*QC_ + h*HD_ + d;
      KSs[d][r] = tof(qkv[base + C_]);     // K
      Vs[r][d]  = tof(qkv[base + 2*C_]);   // V
    }
    __syncthreads();
    float s[4][4] = {};
    for (int d=0; d<64; d++){
      float a[4], bb[4];
      *(float4*)a  = *(const float4*)&Qs[d][ty*4];
      *(float4*)bb = *(const float4*)&KSs[d][tx*4];
      #pragma unroll
      for (int i=0;i<4;i++)
        #pragma unroll
        for (int j=0;j<4;j++) s[i][j] = fmaf(a[i], bb[j], s[i][j]);
    }
    __syncthreads();                       // all K reads done; KSs -> St
    #pragma unroll
    for (int j=0;j<4;j++)
      *(float4*)&KSs[tx*4+j][ty*4] = make_float4(s[0][j], s[1][j], s[2][j], s[3][j]);
    __syncthreads();
    if (tid < 64){                         // per-q-row running max
      float mx = m_s[tid];
      for (int m=0;m<64;m++) mx = fmaxf(mx, KSs[m][tid]);
      a_s[tid] = expf(m_s[tid] - mx);
      m_s[tid] = mx;
    }
    __syncthreads();
    float al[4], mi[4];
    #pragma unroll
    for (int i=0;i<4;i++){ al[i] = a_s[ty*4+i]; mi[i] = m_s[ty*4+i]; }
    float pr[4][4];
    #pragma unroll
    for (int i=0;i<4;i++)
      #pragma unroll
      for (int j=0;j<4;j++){ pr[i][j] = expf(s[i][j] - mi[i]); o[i][j] *= al[i]; }
    #pragma unroll
    for (int j=0;j<4;j++)
      *(float4*)&KSs[tx*4+j][ty*4] = make_float4(pr[0][j], pr[1][j], pr[2][j], pr[3][j]);
    __syncthreads();
    if (tid < 64){                         // running denominator
      float sm = 0.f;
      for (int m=0;m<64;m++) sm += KSs[m][tid];
      l_s[tid] = l_s[tid]*a_s[tid] + sm;
    }
    for (int m=0;m<64;m++){
      float pv[4], vv[4];
      *(float4*)pv = *(const float4*)&KSs[m][ty*4];
      *(float4*)vv = *(const float4*)&Vs[m][tx*4];
      #pragma unroll
      for (int i=0;i<4;i++)
        #pragma unroll
        for (int j=0;j<4;j++) o[i][j] = fmaf(pv[i], vv[j], o[i][j]);
    }
  }
  __syncthreads();
  #pragma unroll
  for (int i=0;i<4;i++){
    const int r = ty*4 + i;
    const float inv_l = 1.0f / l_s[r];
    const size_t rowbase = ((size_t)(b*N_ + (qt<<6) + r))*C_ + h*HD_;
    #pragma unroll
    for (int j=0;j<4;j++)
      attn_out[rowbase + tx*4 + j] = __float2bfloat16(o[i][j] * inv_l);
  }
}

// ---------------------------------------------------------------------------
// ws: [0,256) int flag | qkv bf16 [Mc][2304] | ao bf16 [Mc][768]
// ---------------------------------------------------------------------------
extern "C" void kernel_launch(void* const* d_in, const int* in_sizes, int n_in,
                              void* d_out, int out_size, void* d_ws, size_t ws_size,
                              hipStream_t stream)
{
  (void)in_sizes; (void)n_in; (void)out_size;
  const void* x     = d_in[0];
  const void* Wqkv  = d_in[1];
  const void* bqkv  = d_in[2];
  const void* Wproj = d_in[3];
  const void* bproj = d_in[4];
  const int*  pos_h = (const int*)d_in[5];
  const int*  pos_w = (const int*)d_in[6];

  int* flag = (int*)d_ws;
  char* wsbase = (char*)d_ws + 256;
  const size_t avail = (ws_size > 256) ? ws_size - 256 : 0;

  int CB = 4;
  if (avail < (size_t)4 * 6291456) CB = 2;
  if (avail < (size_t)2 * 6291456) CB = 1;
  const int Mc = CB * N_;

  bf16* qkv = (bf16*)wsbase;                    // [Mc][2304]
  bf16* ao  = qkv + (size_t)Mc * QC_;           // [Mc][768]

  detect_dtype<<<1, 256, 0, stream>>>((const unsigned*)x, flag);

  for (int c0 = 0; c0 < B_; c0 += CB) {
    // 1) qkv = x[rows c0*N ..] @ W_qkv + b_qkv (A rows offset by c0*N)
    gemm_bias_128<<<dim3(Mc/128, QC_/128), 256, 0, stream>>>(
        x, Wqkv, bqkv, qkv, QC_, C_, c0*N_, 0, flag, 2, 2, 1);
    // 2) RoPE in place
    rope_kernel<<<(Mc*768 + 255)/256, 256, 0, stream>>>(
        qkv, pos_h + (size_t)c0*N_, pos_w + (size_t)c0*N_, Mc);
    // 3) flash attention -> ao
    attn_kernel<<<dim3(N_/64, CB*H_), 256, 0, stream>>>(qkv, ao);
    // 4) out[rows c0*N ..] = ao @ W_proj + b_proj
    gemm_bias_128<<<dim3(Mc/128, C_/128), 256, 0, stream>>>(
        ao, Wproj, bproj, d_out, C_, C_, 0, c0*N_, flag, 1, 2, 2);
  }
}

// Round 4
// 1547.449 us; speedup vs baseline: 1.5486x; 1.5486x over previous
//
#include <hip/hip_runtime.h>
#include <hip/hip_bf16.h>

#define B_ 16
#define N_ 1024
#define C_ 768
#define H_ 12
#define HD_ 64
#define QC_ (3*C_)      // 2304

using bf16 = __hip_bfloat16;
using bf16x8 = __attribute__((ext_vector_type(8))) __bf16;
using f32x4  = __attribute__((ext_vector_type(4))) float;

__device__ __forceinline__ float tof(bf16 v){ return __bfloat162float(v); }

// ---------------------------------------------------------------------------
// Input-dtype detector (1=bf16, 0=fp32) from bits 14:7 of sampled words.
// ---------------------------------------------------------------------------
__global__ __launch_bounds__(256) void detect_dtype(
    const unsigned* __restrict__ x32, int* __restrict__ flag)
{
  __shared__ int cnt;
  if (threadIdx.x == 0) cnt = 0;
  __syncthreads();
  int local = 0;
  #pragma unroll
  for (int i = 0; i < 16; i++) {
    unsigned u = x32[threadIdx.x * 16 + i * 4096];
    unsigned e = (u >> 7) & 0xFF;
    local += (e >= 110 && e <= 140) ? 1 : 0;
  }
  atomicAdd(&cnt, local);
  __syncthreads();
  if (threadIdx.x == 0) *flag = (cnt > 2048) ? 1 : 0;
}

// ---------------------------------------------------------------------------
// Cast x (fp32 or bf16 per flag) -> bf16, 4 elems/thread. off4 = elem/4 base.
// ---------------------------------------------------------------------------
__global__ __launch_bounds__(256) void cvt_x(
    const void* __restrict__ x, bf16* __restrict__ xb,
    const int* __restrict__ flag, const int n4, const int off4)
{
  const int i = blockIdx.x * 256 + threadIdx.x;
  if (i >= n4) return;
  if (*flag) {
    ((uint2*)xb)[i] = ((const uint2*)x)[off4 + i];
  } else {
    float4 v = ((const float4*)x)[off4 + i];
    xb[i*4+0] = __float2bfloat16(v.x);
    xb[i*4+1] = __float2bfloat16(v.y);
    xb[i*4+2] = __float2bfloat16(v.z);
    xb[i*4+3] = __float2bfloat16(v.w);
  }
}

// ---------------------------------------------------------------------------
// WT[n][k] (bf16) = W[k][n] (dtype per flag). Tiled 32x32 transpose.
// ---------------------------------------------------------------------------
__global__ __launch_bounds__(256) void wt_cvt(
    const void* __restrict__ W, bf16* __restrict__ WT,
    const int K, const int Nd, const int* __restrict__ flag)
{
  __shared__ float t[32][33];
  const int fl = *flag;
  const int n0 = blockIdx.x * 32, k0 = blockIdx.y * 32;
  const int tx = threadIdx.x & 31, ty = threadIdx.x >> 5;   // 32 x 8
  for (int kk = ty; kk < 32; kk += 8) {
    const size_t gi = (size_t)(k0 + kk) * Nd + (n0 + tx);
    t[kk][tx] = fl ? tof(((const bf16*)W)[gi]) : ((const float*)W)[gi];
  }
  __syncthreads();
  for (int nn = ty; nn < 32; nn += 8)
    WT[(size_t)(n0 + nn) * K + (k0 + tx)] = __float2bfloat16(t[tx][nn]);
}

// ---------------------------------------------------------------------------
// MFMA NT-GEMM: Cout[r][n] = sum_k Ab[r][k] * WT[n][k] + bias[n].
// 128x128 block tile, BK=64, 256 threads (4 waves, each 64x64).
// LDS XOR-swizzle: tile slot (row, j) holds k-chunk (j ^ (row&7)) of 8 bf16,
// so fragment ds_read_b128 spreads over all 32 banks (2-way only = free).
// bias_mode/c_mode: 0=fp32, 1=bf16, 2=follow *flag.
// ---------------------------------------------------------------------------
__global__ __launch_bounds__(256) void gemm_mfma(
    const bf16* __restrict__ Ab, const bf16* __restrict__ WT,
    const void* __restrict__ bias, void* __restrict__ Cout,
    const int Nd, const int K, const int c_row_off,
    const int* __restrict__ flag, const int bias_mode, const int c_mode)
{
  const int fl = *flag;
  const bool bbf = (bias_mode == 2) ? (fl != 0) : (bias_mode != 0);
  const bool cbf = (c_mode == 2) ? (fl != 0) : (c_mode != 0);

  __shared__ __align__(16) unsigned short As[128*64];
  __shared__ __align__(16) unsigned short Bs[128*64];

  const int tid = threadIdx.x;
  const int l   = tid & 63;
  const int w   = tid >> 6;
  const int wm  = (w & 1) * 64;       // wave row base within tile
  const int wn  = (w >> 1) * 64;      // wave col base within tile
  const int row0 = blockIdx.x * 128;
  const int col0 = blockIdx.y * 128;

  // staging: thread t loads rows (i*32 + t>>3), k-chunk (t&7) of 8 bf16;
  // stores into slot j = (t&7)^((t>>3)&7)  (XOR swizzle).
  const int trow  = tid >> 3;               // 0..31
  const int tch   = tid & 7;                // 0..7
  const int slotj = tch ^ (trow & 7);
  const bf16* Aptr = Ab + (size_t)(row0 + trow) * K + tch * 8;
  const bf16* Bptr = WT + (size_t)(col0 + trow) * K + tch * 8;
  const int lA = trow * 64 + slotj * 8;     // element offset; +i*2048 per issue

  f32x4 acc[4][4] = {};

  for (int k0 = 0; k0 < K; k0 += 64) {
    uint4 av[4], bv[4];
    #pragma unroll
    for (int i = 0; i < 4; i++) {
      av[i] = *(const uint4*)(Aptr + (size_t)i*32*K + k0);
      bv[i] = *(const uint4*)(Bptr + (size_t)i*32*K + k0);
    }
    __syncthreads();                 // all waves done reading previous tile
    #pragma unroll
    for (int i = 0; i < 4; i++) {
      *(uint4*)&As[lA + i*2048] = av[i];
      *(uint4*)&Bs[lA + i*2048] = bv[i];
    }
    __syncthreads();
    #pragma unroll
    for (int s = 0; s < 2; s++) {    // two k-steps of 32 within BK=64
      bf16x8 af[4], bg[4];
      const int ch = (s*4 + (l >> 4)) ^ (l & 7);   // swizzled chunk
      #pragma unroll
      for (int i = 0; i < 4; i++) {
        const int rowm = wm + i*16 + (l & 15);
        const int rown = wn + i*16 + (l & 15);
        af[i] = *(const bf16x8*)&As[rowm*64 + ch*8];
        bg[i] = *(const bf16x8*)&Bs[rown*64 + ch*8];
      }
      #pragma unroll
      for (int i = 0; i < 4; i++)
        #pragma unroll
        for (int j = 0; j < 4; j++)
          acc[i][j] = __builtin_amdgcn_mfma_f32_16x16x32_bf16(
                          af[i], bg[j], acc[i][j], 0, 0, 0);
    }
  }

  // Epilogue. C/D layout (m89-verified): col = lane&15, row = (lane>>4)*4+reg.
  const int cn   = col0 + wn + (l & 15);
  const int rbase = c_row_off + row0 + wm + (l >> 4) * 4;
  #pragma unroll
  for (int j = 0; j < 4; j++) {
    const int col = cn + j*16;
    const float bval = bbf ? tof(((const bf16*)bias)[col])
                           : ((const float*)bias)[col];
    #pragma unroll
    for (int i = 0; i < 4; i++) {
      #pragma unroll
      for (int v = 0; v < 4; v++) {
        const size_t r = (size_t)(rbase + i*16 + v);
        const float val = acc[i][j][v] + bval;
        if (cbf) ((bf16*)Cout)[r * Nd + col] = __float2bfloat16(val);
        else     ((float*)Cout)[r * Nd + col] = val;
      }
    }
  }
}

// ---------------------------------------------------------------------------
// RoPE in-place on qkv[M][2304] (bf16).
// ---------------------------------------------------------------------------
__global__ __launch_bounds__(256) void rope_kernel(
    bf16* __restrict__ qkv, const int* __restrict__ pos_h,
    const int* __restrict__ pos_w, const int M)
{
  const int p = blockIdx.x * 256 + threadIdx.x;     // < M*768
  if (p >= M * 768) return;
  const int bn   = p / 768;
  const int rem  = p - bn * 768;
  const int t    = rem / 384;         // 0=q, 1=k
  const int rem2 = rem - t * 384;
  const int h    = rem2 >> 5;
  const int pj   = rem2 & 31;
  const int half = pj >> 4;           // 0: pos_h, 1: pos_w
  const int j    = pj & 15;           // partner at +16
  const int fi   = j >> 1;

  const float pos = (float)((half == 0) ? pos_h[bn] : pos_w[bn]);
  const float LOG2_BASE = 13.287712379549449f;     // log2(10000)
  const float f1 = exp2f(-LOG2_BASE * (float)fi       * (1.0f/16.0f));
  const float f2 = exp2f(-LOG2_BASE * (float)(fi + 8) * (1.0f/16.0f));
  float s1, c1, s2, c2;
  sincosf(pos * f1, &s1, &c1);
  sincosf(pos * f2, &s2, &c2);

  const size_t base = (size_t)bn * QC_ + t * C_ + h * HD_ + half * 32 + j;
  const float v1 = tof(qkv[base]);
  const float v2 = tof(qkv[base + 16]);
  qkv[base]      = __float2bfloat16(v1 * c1 - v2 * s1);
  qkv[base + 16] = __float2bfloat16(v2 * c2 + v1 * s2);
}

// ---------------------------------------------------------------------------
// Flash attention (VALU version, unchanged from round 3). 53 KB LDS.
// ---------------------------------------------------------------------------
__global__ __launch_bounds__(256) void attn_kernel(
    const bf16* __restrict__ qkv, bf16* __restrict__ attn_out)
{
  __shared__ float Qs[64][68];
  __shared__ float KSs[64][68];
  __shared__ float Vs[64][68];
  __shared__ float m_s[64], l_s[64], a_s[64];
  const int tid = threadIdx.x;
  const int tx  = tid & 15;
  const int ty  = tid >> 4;
  const int qt  = blockIdx.x;
  const int bh  = blockIdx.y;
  const int b   = bh / H_;
  const int h   = bh - b * H_;

  #pragma unroll
  for (int i=0;i<16;i++){
    int idx = tid + (i<<8);
    int r = idx >> 6, d = idx & 63;
    Qs[d][r] = 0.125f * tof(qkv[((size_t)(b*N_ + (qt<<6) + r))*QC_ + h*HD_ + d]);
  }
  if (tid < 64){ m_s[tid] = -3.0e38f; l_s[tid] = 0.f; }
  float o[4][4] = {};

  for (int kt=0; kt<16; kt++){
    __syncthreads();
    #pragma unroll
    for (int i=0;i<16;i++){
      int idx = tid + (i<<8);
      int r = idx >> 6, d = idx & 63;
      size_t base = ((size_t)(b*N_ + (kt<<6) + r))*QC_ + h*HD_ + d;
      KSs[d][r] = tof(qkv[base + C_]);
      Vs[r][d]  = tof(qkv[base + 2*C_]);
    }
    __syncthreads();
    float s[4][4] = {};
    for (int d=0; d<64; d++){
      float a[4], bb[4];
      *(float4*)a  = *(const float4*)&Qs[d][ty*4];
      *(float4*)bb = *(const float4*)&KSs[d][tx*4];
      #pragma unroll
      for (int i=0;i<4;i++)
        #pragma unroll
        for (int j=0;j<4;j++) s[i][j] = fmaf(a[i], bb[j], s[i][j]);
    }
    __syncthreads();
    #pragma unroll
    for (int j=0;j<4;j++)
      *(float4*)&KSs[tx*4+j][ty*4] = make_float4(s[0][j], s[1][j], s[2][j], s[3][j]);
    __syncthreads();
    if (tid < 64){
      float mx = m_s[tid];
      for (int m=0;m<64;m++) mx = fmaxf(mx, KSs[m][tid]);
      a_s[tid] = expf(m_s[tid] - mx);
      m_s[tid] = mx;
    }
    __syncthreads();
    float al[4], mi[4];
    #pragma unroll
    for (int i=0;i<4;i++){ al[i] = a_s[ty*4+i]; mi[i] = m_s[ty*4+i]; }
    float pr[4][4];
    #pragma unroll
    for (int i=0;i<4;i++)
      #pragma unroll
      for (int j=0;j<4;j++){ pr[i][j] = expf(s[i][j] - mi[i]); o[i][j] *= al[i]; }
    #pragma unroll
    for (int j=0;j<4;j++)
      *(float4*)&KSs[tx*4+j][ty*4] = make_float4(pr[0][j], pr[1][j], pr[2][j], pr[3][j]);
    __syncthreads();
    if (tid < 64){
      float sm = 0.f;
      for (int m=0;m<64;m++) sm += KSs[m][tid];
      l_s[tid] = l_s[tid]*a_s[tid] + sm;
    }
    for (int m=0;m<64;m++){
      float pv[4], vv[4];
      *(float4*)pv = *(const float4*)&KSs[m][ty*4];
      *(float4*)vv = *(const float4*)&Vs[m][tx*4];
      #pragma unroll
      for (int i=0;i<4;i++)
        #pragma unroll
        for (int j=0;j<4;j++) o[i][j] = fmaf(pv[i], vv[j], o[i][j]);
    }
  }
  __syncthreads();
  #pragma unroll
  for (int i=0;i<4;i++){
    const int r = ty*4 + i;
    const float inv_l = 1.0f / l_s[r];
    const size_t rowbase = ((size_t)(b*N_ + (qt<<6) + r))*C_ + h*HD_;
    #pragma unroll
    for (int j=0;j<4;j++)
      attn_out[rowbase + tx*4 + j] = __float2bfloat16(o[i][j] * inv_l);
  }
}

// ---------------------------------------------------------------------------
// ws: flag(256B) | WqkvT bf16 [2304][768] | WprojT bf16 [768][768]
//     | xb bf16 [Mc][768] | qkv bf16 [Mc][2304] | ao bf16 [Mc][768]
// per-batch chunk cost 7,864,320 B; fixed 4,718,848 B.
// ---------------------------------------------------------------------------
extern "C" void kernel_launch(void* const* d_in, const int* in_sizes, int n_in,
                              void* d_out, int out_size, void* d_ws, size_t ws_size,
                              hipStream_t stream)
{
  (void)in_sizes; (void)n_in; (void)out_size;
  const void* x     = d_in[0];
  const void* Wqkv  = d_in[1];
  const void* bqkv  = d_in[2];
  const void* Wproj = d_in[3];
  const void* bproj = d_in[4];
  const int*  pos_h = (const int*)d_in[5];
  const int*  pos_w = (const int*)d_in[6];

  int* flag = (int*)d_ws;
  char* p = (char*)d_ws + 256;
  bf16* WqkvT  = (bf16*)p; p += (size_t)QC_ * C_ * 2;
  bf16* WprojT = (bf16*)p; p += (size_t)C_ * C_ * 2;

  const size_t fixed = 256 + (size_t)QC_*C_*2 + (size_t)C_*C_*2;
  const size_t perb  = (size_t)N_*C_*2 + (size_t)N_*QC_*2 + (size_t)N_*C_*2;
  int CB = 4;
  if (ws_size < fixed + 4*perb) CB = 2;
  if (ws_size < fixed + 2*perb) CB = 1;
  const int Mc = CB * N_;

  bf16* xb  = (bf16*)p; p += (size_t)Mc * C_ * 2;
  bf16* qkv = (bf16*)p; p += (size_t)Mc * QC_ * 2;
  bf16* ao  = (bf16*)p;

  detect_dtype<<<1, 256, 0, stream>>>((const unsigned*)x, flag);
  wt_cvt<<<dim3(QC_/32, C_/32), 256, 0, stream>>>(Wqkv, WqkvT, C_, QC_, flag);
  wt_cvt<<<dim3(C_/32,  C_/32), 256, 0, stream>>>(Wproj, WprojT, C_, C_, flag);

  for (int c0 = 0; c0 < B_; c0 += CB) {
    const int n4 = Mc * C_ / 4;
    cvt_x<<<(n4 + 255)/256, 256, 0, stream>>>(x, xb, flag, n4, c0 * N_ * C_ / 4);
    // qkv = xb @ Wqkv + b_qkv  (bf16 out)
    gemm_mfma<<<dim3(Mc/128, QC_/128), 256, 0, stream>>>(
        xb, WqkvT, bqkv, qkv, QC_, C_, 0, flag, 2, 1);
    rope_kernel<<<(Mc*768 + 255)/256, 256, 0, stream>>>(
        qkv, pos_h + (size_t)c0*N_, pos_w + (size_t)c0*N_, Mc);
    attn_kernel<<<dim3(N_/64, CB*H_), 256, 0, stream>>>(qkv, ao);
    // out = ao @ Wproj + b_proj  (dtype per flag)
    gemm_mfma<<<dim3(Mc/128, C_/128), 256, 0, stream>>>(
        ao, WprojT, bproj, d_out, C_, C_, c0*N_, flag, 2, 2);
  }
}

// Round 5
// 867.566 us; speedup vs baseline: 2.7622x; 1.7837x over previous
//
#include <hip/hip_runtime.h>
#include <hip/hip_bf16.h>

#define B_ 16
#define N_ 1024
#define C_ 768
#define H_ 12
#define HD_ 64
#define QC_ (3*C_)      // 2304

using bf16 = __hip_bfloat16;
using bf16x8 = __attribute__((ext_vector_type(8))) __bf16;
using f32x4  = __attribute__((ext_vector_type(4))) float;

__device__ __forceinline__ float tof(bf16 v){ return __bfloat162float(v); }

// ---------------------------------------------------------------------------
// Input-dtype detector (1=bf16, 0=fp32) from bits 14:7 of sampled words.
// ---------------------------------------------------------------------------
__global__ __launch_bounds__(256) void detect_dtype(
    const unsigned* __restrict__ x32, int* __restrict__ flag)
{
  __shared__ int cnt;
  if (threadIdx.x == 0) cnt = 0;
  __syncthreads();
  int local = 0;
  #pragma unroll
  for (int i = 0; i < 16; i++) {
    unsigned u = x32[threadIdx.x * 16 + i * 4096];
    unsigned e = (u >> 7) & 0xFF;
    local += (e >= 110 && e <= 140) ? 1 : 0;
  }
  atomicAdd(&cnt, local);
  __syncthreads();
  if (threadIdx.x == 0) *flag = (cnt > 2048) ? 1 : 0;
}

// ---------------------------------------------------------------------------
// Cast x (fp32 or bf16 per flag) -> bf16, 4 elems/thread.
// ---------------------------------------------------------------------------
__global__ __launch_bounds__(256) void cvt_x(
    const void* __restrict__ x, bf16* __restrict__ xb,
    const int* __restrict__ flag, const int n4, const int off4)
{
  const int i = blockIdx.x * 256 + threadIdx.x;
  if (i >= n4) return;
  if (*flag) {
    ((uint2*)xb)[i] = ((const uint2*)x)[off4 + i];
  } else {
    float4 v = ((const float4*)x)[off4 + i];
    xb[i*4+0] = __float2bfloat16(v.x);
    xb[i*4+1] = __float2bfloat16(v.y);
    xb[i*4+2] = __float2bfloat16(v.z);
    xb[i*4+3] = __float2bfloat16(v.w);
  }
}

// ---------------------------------------------------------------------------
// WT[n][k] (bf16) = W[k][n] (dtype per flag). Tiled 32x32 transpose.
// ---------------------------------------------------------------------------
__global__ __launch_bounds__(256) void wt_cvt(
    const void* __restrict__ W, bf16* __restrict__ WT,
    const int K, const int Nd, const int* __restrict__ flag)
{
  __shared__ float t[32][33];
  const int fl = *flag;
  const int n0 = blockIdx.x * 32, k0 = blockIdx.y * 32;
  const int tx = threadIdx.x & 31, ty = threadIdx.x >> 5;   // 32 x 8
  for (int kk = ty; kk < 32; kk += 8) {
    const size_t gi = (size_t)(k0 + kk) * Nd + (n0 + tx);
    t[kk][tx] = fl ? tof(((const bf16*)W)[gi]) : ((const float*)W)[gi];
  }
  __syncthreads();
  for (int nn = ty; nn < 32; nn += 8)
    WT[(size_t)(n0 + nn) * K + (k0 + tx)] = __float2bfloat16(t[tx][nn]);
}

// ---------------------------------------------------------------------------
// Fused qkv GEMM + bias + RoPE + layout scatter.
//   A = xb [Mc][768] bf16, W = WqkvT [2304][768] bf16.
// Outputs: Qp[bh][n][64] (rope'd, x0.125), Kp[bh][n][64] (rope'd),
//          Vt[bh][64][n] (transposed).  bh = chunk-local b*12 + h.
// The wave's 4 j-columns are dd0, dd0+16, dd0+32, dd0+48 of ONE head =
// exactly the RoPE rotation pairs -> rope applied in-register.
// ---------------------------------------------------------------------------
__global__ __launch_bounds__(256) void gemm_qkv_rope(
    const bf16* __restrict__ Ab, const bf16* __restrict__ WT,
    const void* __restrict__ bias, bf16* __restrict__ Qp,
    bf16* __restrict__ Kp, bf16* __restrict__ Vtb,
    const int* __restrict__ flag,
    const int* __restrict__ pos_h, const int* __restrict__ pos_w)
{
  const int Nd = QC_, K = C_;
  const bool bbf = (*flag != 0);

  __shared__ __align__(16) unsigned short As[128*64];
  __shared__ __align__(16) unsigned short Bs[128*64];

  const int tid = threadIdx.x;
  const int l   = tid & 63;
  const int w   = tid >> 6;
  const int wm  = (w & 1) * 64;
  const int wn  = (w >> 1) * 64;
  const int row0 = blockIdx.x * 128;
  const int col0 = blockIdx.y * 128;

  const int trow  = tid >> 3;
  const int tch   = tid & 7;
  const int slotj = tch ^ (trow & 7);
  const bf16* Aptr = Ab + (size_t)(row0 + trow) * K + tch * 8;
  const bf16* Bptr = WT + (size_t)(col0 + trow) * K + tch * 8;
  const int lA = trow * 64 + slotj * 8;

  f32x4 acc[4][4] = {};

  for (int k0 = 0; k0 < K; k0 += 64) {
    uint4 av[4], bv[4];
    #pragma unroll
    for (int i = 0; i < 4; i++) {
      av[i] = *(const uint4*)(Aptr + (size_t)i*32*K + k0);
      bv[i] = *(const uint4*)(Bptr + (size_t)i*32*K + k0);
    }
    __syncthreads();
    #pragma unroll
    for (int i = 0; i < 4; i++) {
      *(uint4*)&As[lA + i*2048] = av[i];
      *(uint4*)&Bs[lA + i*2048] = bv[i];
    }
    __syncthreads();
    #pragma unroll
    for (int s = 0; s < 2; s++) {
      bf16x8 af[4], bg[4];
      const int ch = (s*4 + (l >> 4)) ^ (l & 7);
      #pragma unroll
      for (int i = 0; i < 4; i++) {
        const int rowm = wm + i*16 + (l & 15);
        const int rown = wn + i*16 + (l & 15);
        af[i] = *(const bf16x8*)&As[rowm*64 + ch*8];
        bg[i] = *(const bf16x8*)&Bs[rown*64 + ch*8];
      }
      #pragma unroll
      for (int i = 0; i < 4; i++)
        #pragma unroll
        for (int j = 0; j < 4; j++)
          acc[i][j] = __builtin_amdgcn_mfma_f32_16x16x32_bf16(
                          af[i], bg[j], acc[i][j], 0, 0, 0);
    }
  }

  // ---- fused epilogue ----
  const int colbase = col0 + wn;            // multiple of 64
  const int t   = colbase / 768;            // 0=q 1=k 2=v (wave-uniform)
  const int h   = (colbase % 768) >> 6;     // head (wave-uniform)
  const int dd0 = l & 15;
  const int fi  = dd0 >> 1;
  const float LOG2B = 13.287712379549449f;  // log2(10000)
  const float f1 = exp2f(-LOG2B * (float)fi       * (1.0f/16.0f));
  const float f2 = exp2f(-LOG2B * (float)(fi + 8) * (1.0f/16.0f));
  float bv4[4];
  #pragma unroll
  for (int j = 0; j < 4; j++) {
    const int c = colbase + dd0 + j*16;
    bv4[j] = bbf ? tof(((const bf16*)bias)[c]) : ((const float*)bias)[c];
  }
  const int rb = row0 + wm + (l >> 4) * 4;

  #pragma unroll
  for (int i = 0; i < 4; i++) {
    #pragma unroll
    for (int v = 0; v < 4; v++) {
      const int r  = rb + i*16 + v;          // chunk-local row
      const int bp = r >> 10;
      const int n  = r & 1023;
      float y0 = acc[i][0][v] + bv4[0];
      float y1 = acc[i][1][v] + bv4[1];
      float y2 = acc[i][2][v] + bv4[2];
      float y3 = acc[i][3][v] + bv4[3];
      if (t == 2) {
        const size_t vb0 = (size_t)(bp*12 + h) * 65536 + n;
        Vtb[vb0 + (size_t)(dd0     ) * 1024] = __float2bfloat16(y0);
        Vtb[vb0 + (size_t)(dd0 + 16) * 1024] = __float2bfloat16(y1);
        Vtb[vb0 + (size_t)(dd0 + 32) * 1024] = __float2bfloat16(y2);
        Vtb[vb0 + (size_t)(dd0 + 48) * 1024] = __float2bfloat16(y3);
      } else {
        const float ph = (float)pos_h[r];
        const float pw = (float)pos_w[r];
        float s1,c1,s2,c2,s3,c3,s4,c4;
        __sincosf(ph*f1, &s1, &c1);
        __sincosf(ph*f2, &s2, &c2);
        __sincosf(pw*f1, &s3, &c3);
        __sincosf(pw*f2, &s4, &c4);
        float z0 = y0*c1 - y1*s1;
        float z1 = y1*c2 + y0*s2;
        float z2 = y2*c3 - y3*s3;
        float z3 = y3*c4 + y2*s4;
        if (t == 0) { z0*=0.125f; z1*=0.125f; z2*=0.125f; z3*=0.125f; }
        bf16* dst = (t == 0) ? Qp : Kp;
        const size_t qb = ((size_t)(bp*12 + h) * 1024 + n) * 64 + dd0;
        dst[qb     ] = __float2bfloat16(z0);
        dst[qb + 16] = __float2bfloat16(z1);
        dst[qb + 32] = __float2bfloat16(z2);
        dst[qb + 48] = __float2bfloat16(z3);
      }
    }
  }
}

// ---------------------------------------------------------------------------
// MFMA flash attention. Block = (q-tile of 64, bh). 4 waves; wave owns 16
// q-rows. All LDS tiles XOR-swizzled (chunk' = chunk ^ (row&7)) so every
// ds_read_b128 fragment access is at the bank floor.
// ---------------------------------------------------------------------------
__global__ __launch_bounds__(256) void attn_mfma(
    const bf16* __restrict__ Qp, const bf16* __restrict__ Kp,
    const bf16* __restrict__ Vtb, bf16* __restrict__ ao)
{
  __shared__ __align__(16) bf16 Qs[64*64];
  __shared__ __align__(16) bf16 Ks[64*64];
  __shared__ __align__(16) bf16 Vs[64*64];   // V^T tile: rows=d, cols=kk
  __shared__ __align__(16) bf16 Ps[64*64];   // P, per-wave 16-row regions
  const int tid = threadIdx.x;
  const int l   = tid & 63;
  const int w   = tid >> 6;
  const int qt  = blockIdx.x;                // 0..15
  const int bh  = blockIdx.y;                // chunk-local b*12 + h
  const size_t base = (size_t)bh * 65536;

  // stage Q tile (swizzled)
  #pragma unroll
  for (int i = 0; i < 2; i++) {
    const int idx = tid + i*256;
    const int row = idx >> 3, ch = idx & 7;
    const int slot = ch ^ (row & 7);
    *(uint4*)&Qs[row*64 + slot*8] =
        *(const uint4*)(Qp + base + (size_t)(qt*64 + row)*64 + ch*8);
  }
  __syncthreads();

  bf16x8 af[2];
  {
    const int row = w*16 + (l & 15);
    #pragma unroll
    for (int s = 0; s < 2; s++) {
      const int ch = (s*4 + (l >> 4)) ^ (row & 7);
      af[s] = *(const bf16x8*)&Qs[row*64 + ch*8];
    }
  }

  float m_i[4], l_i[4];
  #pragma unroll
  for (int v = 0; v < 4; v++) { m_i[v] = -3.0e38f; l_i[v] = 0.f; }
  f32x4 o[4] = {};

  for (int kt = 0; kt < 16; kt++) {
    __syncthreads();                         // prev iter done with Ks/Vs
    #pragma unroll
    for (int i = 0; i < 2; i++) {
      const int idx = tid + i*256;
      const int row = idx >> 3, ch = idx & 7;
      const int slot = ch ^ (row & 7);
      *(uint4*)&Ks[row*64 + slot*8] =
          *(const uint4*)(Kp + base + (size_t)(kt*64 + row)*64 + ch*8);
      *(uint4*)&Vs[row*64 + slot*8] =
          *(const uint4*)(Vtb + base + (size_t)row*1024 + kt*64 + ch*8);
    }
    __syncthreads();

    // S = Q K^T (Q pre-scaled). 4 kk-tiles of 16.
    f32x4 s[4];
    #pragma unroll
    for (int nt = 0; nt < 4; nt++) {
      f32x4 a = {};
      const int nrow = nt*16 + (l & 15);
      #pragma unroll
      for (int ss = 0; ss < 2; ss++) {
        const int ch = (ss*4 + (l >> 4)) ^ (nrow & 7);
        bf16x8 bg = *(const bf16x8*)&Ks[nrow*64 + ch*8];
        a = __builtin_amdgcn_mfma_f32_16x16x32_bf16(af[ss], bg, a, 0, 0, 0);
      }
      s[nt] = a;
    }

    // online softmax; lane's rows: w*16 + (l>>4)*4 + v
    #pragma unroll
    for (int v = 0; v < 4; v++) {
      float m0 = fmaxf(fmaxf(s[0][v], s[1][v]), fmaxf(s[2][v], s[3][v]));
      #pragma unroll
      for (int off = 1; off < 16; off <<= 1)
        m0 = fmaxf(m0, __shfl_xor(m0, off));
      const float mx = fmaxf(m_i[v], m0);
      const float alpha = exp2f((m_i[v] - mx) * 1.4426950408889634f);
      m_i[v] = mx;
      float r = 0.f;
      #pragma unroll
      for (int nt = 0; nt < 4; nt++) {
        const float p = exp2f((s[nt][v] - mx) * 1.4426950408889634f);
        s[nt][v] = p;
        r += p;
      }
      #pragma unroll
      for (int off = 1; off < 16; off <<= 1)
        r += __shfl_xor(r, off);
      l_i[v] = l_i[v] * alpha + r;
      #pragma unroll
      for (int nt = 0; nt < 4; nt++) o[nt][v] *= alpha;
    }

    // P -> bf16 -> Ps (own wave's rows; no cross-wave sharing)
    #pragma unroll
    for (int nt = 0; nt < 4; nt++) {
      const int kk = nt*16 + (l & 15);
      #pragma unroll
      for (int v = 0; v < 4; v++) {
        const int row = w*16 + (l >> 4)*4 + v;
        const int ch  = (kk >> 3) ^ (row & 7);
        Ps[row*64 + ch*8 + (kk & 7)] = __float2bfloat16(s[nt][v]);
      }
    }

    // O += P V  (A-frags from Ps, B-frags from swizzled V^T)
    #pragma unroll
    for (int ss = 0; ss < 2; ss++) {
      const int prow = w*16 + (l & 15);
      const int pch  = (ss*4 + (l >> 4)) ^ (prow & 7);
      bf16x8 pa = *(const bf16x8*)&Ps[prow*64 + pch*8];
      #pragma unroll
      for (int ntd = 0; ntd < 4; ntd++) {
        const int drow = ntd*16 + (l & 15);
        const int vch  = (ss*4 + (l >> 4)) ^ (drow & 7);
        bf16x8 vb = *(const bf16x8*)&Vs[drow*64 + vch*8];
        o[ntd] = __builtin_amdgcn_mfma_f32_16x16x32_bf16(pa, vb, o[ntd], 0,0,0);
      }
    }
  }

  // epilogue: normalize, store ao[chunk row][h*64+d]
  const int b = bh / 12, h = bh - b*12;
  #pragma unroll
  for (int v = 0; v < 4; v++) {
    const int r = qt*64 + w*16 + (l >> 4)*4 + v;
    const float inv = 1.0f / l_i[v];
    const size_t rowbase = ((size_t)(b*1024 + r)) * 768 + h*64;
    #pragma unroll
    for (int ntd = 0; ntd < 4; ntd++)
      ao[rowbase + ntd*16 + (l & 15)] = __float2bfloat16(o[ntd][v] * inv);
  }
}

// ---------------------------------------------------------------------------
// Plain MFMA NT-GEMM + bias (proj). Unchanged from round 4 (verified).
// ---------------------------------------------------------------------------
__global__ __launch_bounds__(256) void gemm_mfma(
    const bf16* __restrict__ Ab, const bf16* __restrict__ WT,
    const void* __restrict__ bias, void* __restrict__ Cout,
    const int Nd, const int K, const int c_row_off,
    const int* __restrict__ flag, const int bias_mode, const int c_mode)
{
  const int fl = *flag;
  const bool bbf = (bias_mode == 2) ? (fl != 0) : (bias_mode != 0);
  const bool cbf = (c_mode == 2) ? (fl != 0) : (c_mode != 0);

  __shared__ __align__(16) unsigned short As[128*64];
  __shared__ __align__(16) unsigned short Bs[128*64];

  const int tid = threadIdx.x;
  const int l   = tid & 63;
  const int w   = tid >> 6;
  const int wm  = (w & 1) * 64;
  const int wn  = (w >> 1) * 64;
  const int row0 = blockIdx.x * 128;
  const int col0 = blockIdx.y * 128;

  const int trow  = tid >> 3;
  const int tch   = tid & 7;
  const int slotj = tch ^ (trow & 7);
  const bf16* Aptr = Ab + (size_t)(row0 + trow) * K + tch * 8;
  const bf16* Bptr = WT + (size_t)(col0 + trow) * K + tch * 8;
  const int lA = trow * 64 + slotj * 8;

  f32x4 acc[4][4] = {};

  for (int k0 = 0; k0 < K; k0 += 64) {
    uint4 av[4], bv[4];
    #pragma unroll
    for (int i = 0; i < 4; i++) {
      av[i] = *(const uint4*)(Aptr + (size_t)i*32*K + k0);
      bv[i] = *(const uint4*)(Bptr + (size_t)i*32*K + k0);
    }
    __syncthreads();
    #pragma unroll
    for (int i = 0; i < 4; i++) {
      *(uint4*)&As[lA + i*2048] = av[i];
      *(uint4*)&Bs[lA + i*2048] = bv[i];
    }
    __syncthreads();
    #pragma unroll
    for (int s = 0; s < 2; s++) {
      bf16x8 af[4], bg[4];
      const int ch = (s*4 + (l >> 4)) ^ (l & 7);
      #pragma unroll
      for (int i = 0; i < 4; i++) {
        const int rowm = wm + i*16 + (l & 15);
        const int rown = wn + i*16 + (l & 15);
        af[i] = *(const bf16x8*)&As[rowm*64 + ch*8];
        bg[i] = *(const bf16x8*)&Bs[rown*64 + ch*8];
      }
      #pragma unroll
      for (int i = 0; i < 4; i++)
        #pragma unroll
        for (int j = 0; j < 4; j++)
          acc[i][j] = __builtin_amdgcn_mfma_f32_16x16x32_bf16(
                          af[i], bg[j], acc[i][j], 0, 0, 0);
    }
  }

  const int cn    = col0 + wn + (l & 15);
  const int rbase = c_row_off + row0 + wm + (l >> 4) * 4;
  #pragma unroll
  for (int j = 0; j < 4; j++) {
    const int col = cn + j*16;
    const float bval = bbf ? tof(((const bf16*)bias)[col])
                           : ((const float*)bias)[col];
    #pragma unroll
    for (int i = 0; i < 4; i++) {
      #pragma unroll
      for (int v = 0; v < 4; v++) {
        const size_t r = (size_t)(rbase + i*16 + v);
        const float val = acc[i][j][v] + bval;
        if (cbf) ((bf16*)Cout)[r * Nd + col] = __float2bfloat16(val);
        else     ((float*)Cout)[r * Nd + col] = val;
      }
    }
  }
}

// ---------------------------------------------------------------------------
// ws: flag(256B) | WqkvT 3.54MB | WprojT 1.18MB |
//     xb | Qp | Kp | Vt | ao  (each CB*1.57MB)  => 7.86MB per batch
// ---------------------------------------------------------------------------
extern "C" void kernel_launch(void* const* d_in, const int* in_sizes, int n_in,
                              void* d_out, int out_size, void* d_ws, size_t ws_size,
                              hipStream_t stream)
{
  (void)in_sizes; (void)n_in; (void)out_size;
  const void* x     = d_in[0];
  const void* Wqkv  = d_in[1];
  const void* bqkv  = d_in[2];
  const void* Wproj = d_in[3];
  const void* bproj = d_in[4];
  const int*  pos_h = (const int*)d_in[5];
  const int*  pos_w = (const int*)d_in[6];

  int* flag = (int*)d_ws;
  char* p = (char*)d_ws + 256;
  bf16* WqkvT  = (bf16*)p; p += (size_t)QC_ * C_ * 2;
  bf16* WprojT = (bf16*)p; p += (size_t)C_ * C_ * 2;

  const size_t fixed = 256 + (size_t)QC_*C_*2 + (size_t)C_*C_*2;
  const size_t perb  = 5 * (size_t)N_ * C_ * 2;   // xb,Qp,Kp,Vt,ao
  int CB = 4;
  if (ws_size < fixed + 4*perb) CB = 2;
  if (ws_size < fixed + 2*perb) CB = 1;
  const int Mc = CB * N_;
  const size_t tsz = (size_t)Mc * C_;            // elems per per-chunk tensor

  bf16* xb  = (bf16*)p;
  bf16* Qp  = xb  + tsz;
  bf16* Kp  = Qp  + tsz;
  bf16* Vtb = Kp  + tsz;
  bf16* ao  = Vtb + tsz;

  detect_dtype<<<1, 256, 0, stream>>>((const unsigned*)x, flag);
  wt_cvt<<<dim3(QC_/32, C_/32), 256, 0, stream>>>(Wqkv, WqkvT, C_, QC_, flag);
  wt_cvt<<<dim3(C_/32,  C_/32), 256, 0, stream>>>(Wproj, WprojT, C_, C_, flag);

  for (int c0 = 0; c0 < B_; c0 += CB) {
    const int n4 = Mc * C_ / 4;
    cvt_x<<<(n4 + 255)/256, 256, 0, stream>>>(x, xb, flag, n4, c0 * N_ * C_ / 4);
    gemm_qkv_rope<<<dim3(Mc/128, QC_/128), 256, 0, stream>>>(
        xb, WqkvT, bqkv, Qp, Kp, Vtb, flag,
        pos_h + (size_t)c0*N_, pos_w + (size_t)c0*N_);
    attn_mfma<<<dim3(N_/64, CB*H_), 256, 0, stream>>>(Qp, Kp, Vtb, ao);
    gemm_mfma<<<dim3(Mc/128, C_/128), 256, 0, stream>>>(
        ao, WprojT, bproj, d_out, C_, C_, c0*N_, flag, 2, 2);
  }
}

// Round 6
// 856.253 us; speedup vs baseline: 2.7987x; 1.0132x over previous
//
#include <hip/hip_runtime.h>
#include <hip/hip_bf16.h>

#define B_ 16
#define N_ 1024
#define C_ 768
#define H_ 12
#define HD_ 64
#define QC_ (3*C_)      // 2304

using bf16 = __hip_bfloat16;
using bf16x8 = __attribute__((ext_vector_type(8))) __bf16;
using f32x4  = __attribute__((ext_vector_type(4))) float;

__device__ __forceinline__ float tof(bf16 v){ return __bfloat162float(v); }

// ---------------------------------------------------------------------------
// Input-dtype detector (1=bf16, 0=fp32) from bits 14:7 of sampled words.
// ---------------------------------------------------------------------------
__global__ __launch_bounds__(256) void detect_dtype(
    const unsigned* __restrict__ x32, int* __restrict__ flag)
{
  __shared__ int cnt;
  if (threadIdx.x == 0) cnt = 0;
  __syncthreads();
  int local = 0;
  #pragma unroll
  for (int i = 0; i < 16; i++) {
    unsigned u = x32[threadIdx.x * 16 + i * 4096];
    unsigned e = (u >> 7) & 0xFF;
    local += (e >= 110 && e <= 140) ? 1 : 0;
  }
  atomicAdd(&cnt, local);
  __syncthreads();
  if (threadIdx.x == 0) *flag = (cnt > 2048) ? 1 : 0;
}

// ---------------------------------------------------------------------------
// Cast x (fp32 or bf16 per flag) -> bf16, 4 elems/thread.
// ---------------------------------------------------------------------------
__global__ __launch_bounds__(256) void cvt_x(
    const void* __restrict__ x, bf16* __restrict__ xb,
    const int* __restrict__ flag, const int n4, const int off4)
{
  const int i = blockIdx.x * 256 + threadIdx.x;
  if (i >= n4) return;
  if (*flag) {
    ((uint2*)xb)[i] = ((const uint2*)x)[off4 + i];
  } else {
    float4 v = ((const float4*)x)[off4 + i];
    xb[i*4+0] = __float2bfloat16(v.x);
    xb[i*4+1] = __float2bfloat16(v.y);
    xb[i*4+2] = __float2bfloat16(v.z);
    xb[i*4+3] = __float2bfloat16(v.w);
  }
}

// ---------------------------------------------------------------------------
// WT[n][k] (bf16) = W[k][n] (dtype per flag). Tiled 32x32 transpose.
// ---------------------------------------------------------------------------
__global__ __launch_bounds__(256) void wt_cvt(
    const void* __restrict__ W, bf16* __restrict__ WT,
    const int K, const int Nd, const int* __restrict__ flag)
{
  __shared__ float t[32][33];
  const int fl = *flag;
  const int n0 = blockIdx.x * 32, k0 = blockIdx.y * 32;
  const int tx = threadIdx.x & 31, ty = threadIdx.x >> 5;   // 32 x 8
  for (int kk = ty; kk < 32; kk += 8) {
    const size_t gi = (size_t)(k0 + kk) * Nd + (n0 + tx);
    t[kk][tx] = fl ? tof(((const bf16*)W)[gi]) : ((const float*)W)[gi];
  }
  __syncthreads();
  for (int nn = ty; nn < 32; nn += 8)
    WT[(size_t)(n0 + nn) * K + (k0 + tx)] = __float2bfloat16(t[tx][nn]);
}

// ---------------------------------------------------------------------------
// Fused qkv GEMM + bias + RoPE + layout scatter.
// Outputs: Qp[bh][n][64] (rope'd, x0.125), Kp[bh][n][64] (rope'd),
//          Vt[bh][64][n] (transposed via LDS -> coalesced 128B stores).
// t = colbase/768 is BLOCK-uniform (768 = 6 x 128-col tiles per tensor).
// ---------------------------------------------------------------------------
__global__ __launch_bounds__(256) void gemm_qkv_rope(
    const bf16* __restrict__ Ab, const bf16* __restrict__ WT,
    const void* __restrict__ bias, bf16* __restrict__ Qp,
    bf16* __restrict__ Kp, bf16* __restrict__ Vtb,
    const int* __restrict__ flag,
    const int* __restrict__ pos_h, const int* __restrict__ pos_w)
{
  const int K = C_;
  const bool bbf = (*flag != 0);

  // 36 KB raw: [0,16K) As, [16K,32K) Bs during K-loop;
  // reused as 4 x 9216 B per-wave transpose scratch in the V epilogue.
  __shared__ __align__(16) char smem[36864];
  unsigned short* As = (unsigned short*)smem;
  unsigned short* Bs = (unsigned short*)(smem + 16384);

  const int tid = threadIdx.x;
  const int l   = tid & 63;
  const int w   = tid >> 6;
  const int wm  = (w & 1) * 64;
  const int wn  = (w >> 1) * 64;
  const int row0 = blockIdx.x * 128;
  const int col0 = blockIdx.y * 128;

  const int trow  = tid >> 3;
  const int tch   = tid & 7;
  const int slotj = tch ^ (trow & 7);
  const bf16* Aptr = Ab + (size_t)(row0 + trow) * K + tch * 8;
  const bf16* Bptr = WT + (size_t)(col0 + trow) * K + tch * 8;
  const int lA = trow * 64 + slotj * 8;

  f32x4 acc[4][4] = {};

  for (int k0 = 0; k0 < K; k0 += 64) {
    uint4 av[4], bv[4];
    #pragma unroll
    for (int i = 0; i < 4; i++) {
      av[i] = *(const uint4*)(Aptr + (size_t)i*32*K + k0);
      bv[i] = *(const uint4*)(Bptr + (size_t)i*32*K + k0);
    }
    __syncthreads();
    #pragma unroll
    for (int i = 0; i < 4; i++) {
      *(uint4*)&As[lA + i*2048] = av[i];
      *(uint4*)&Bs[lA + i*2048] = bv[i];
    }
    __syncthreads();
    #pragma unroll
    for (int s = 0; s < 2; s++) {
      bf16x8 af[4], bg[4];
      const int ch = (s*4 + (l >> 4)) ^ (l & 7);
      #pragma unroll
      for (int i = 0; i < 4; i++) {
        const int rowm = wm + i*16 + (l & 15);
        const int rown = wn + i*16 + (l & 15);
        af[i] = *(const bf16x8*)&As[rowm*64 + ch*8];
        bg[i] = *(const bf16x8*)&Bs[rown*64 + ch*8];
      }
      #pragma unroll
      for (int i = 0; i < 4; i++)
        #pragma unroll
        for (int j = 0; j < 4; j++)
          acc[i][j] = __builtin_amdgcn_mfma_f32_16x16x32_bf16(
                          af[i], bg[j], acc[i][j], 0, 0, 0);
    }
  }

  // ---- fused epilogue ----
  const int colbase = col0 + wn;            // multiple of 64
  const int t   = colbase / 768;            // 0=q 1=k 2=v (block-uniform)
  const int h   = (colbase % 768) >> 6;     // head (wave-uniform)
  const int dd0 = l & 15;
  float bv4[4];
  #pragma unroll
  for (int j = 0; j < 4; j++) {
    const int c = colbase + dd0 + j*16;
    bv4[j] = bbf ? tof(((const bf16*)bias)[c]) : ((const float*)bias)[c];
  }
  const int rb = row0 + wm + (l >> 4) * 4;

  if (t == 2) {
    // ---- V: in-LDS transpose, then coalesced V^T stores ----
    __syncthreads();                         // As/Bs dead for ALL waves
    bf16* Ts = (bf16*)(smem + w * 9216);     // 64 rows x 72 elems (144 B)
    #pragma unroll
    for (int i = 0; i < 4; i++) {
      #pragma unroll
      for (int v = 0; v < 4; v++) {
        const int nl = i*16 + ((l >> 4) << 2) + v;   // n_local 0..63
        #pragma unroll
        for (int j = 0; j < 4; j++) {
          const int dl = dd0 + j*16;                 // d_local 0..63
          const float y = acc[i][j][v] + bv4[j];
          Ts[dl*72 + (((nl >> 3) ^ (dl & 7)) << 3) + (nl & 7)] =
              __float2bfloat16(y);
        }
      }
    }
    __syncthreads();                         // ds_writes visible (in-block)
    const int n0 = (row0 + wm) & 1023;
    const int bp = (row0 + wm) >> 10;
    const size_t gbase = (size_t)(bp*12 + h) * 65536;   // [bh][64][1024]
    #pragma unroll
    for (int dr = 0; dr < 8; dr++) {
      const int dl = dr*8 + (l >> 3);
      const int c  = l & 7;                  // logical 8-elem chunk
      uint4 vv = *(const uint4*)&Ts[dl*72 + ((c ^ (dl & 7)) << 3)];
      *(uint4*)&Vtb[gbase + (size_t)dl*1024 + n0 + c*8] = vv;
    }
  } else {
    // ---- Q/K: RoPE in-register, row-major stores (line-filling) ----
    const int fi  = dd0 >> 1;
    const float LOG2B = 13.287712379549449f;  // log2(10000)
    const float f1 = exp2f(-LOG2B * (float)fi       * (1.0f/16.0f));
    const float f2 = exp2f(-LOG2B * (float)(fi + 8) * (1.0f/16.0f));
    #pragma unroll
    for (int i = 0; i < 4; i++) {
      #pragma unroll
      for (int v = 0; v < 4; v++) {
        const int r  = rb + i*16 + v;          // chunk-local row
        const int bp = r >> 10;
        const int n  = r & 1023;
        float y0 = acc[i][0][v] + bv4[0];
        float y1 = acc[i][1][v] + bv4[1];
        float y2 = acc[i][2][v] + bv4[2];
        float y3 = acc[i][3][v] + bv4[3];
        const float ph = (float)pos_h[r];
        const float pw = (float)pos_w[r];
        float s1,c1,s2,c2,s3,c3,s4,c4;
        __sincosf(ph*f1, &s1, &c1);
        __sincosf(ph*f2, &s2, &c2);
        __sincosf(pw*f1, &s3, &c3);
        __sincosf(pw*f2, &s4, &c4);
        float z0 = y0*c1 - y1*s1;
        float z1 = y1*c2 + y0*s2;
        float z2 = y2*c3 - y3*s3;
        float z3 = y3*c4 + y2*s4;
        if (t == 0) { z0*=0.125f; z1*=0.125f; z2*=0.125f; z3*=0.125f; }
        bf16* dst = (t == 0) ? Qp : Kp;
        const size_t qb = ((size_t)(bp*12 + h) * 1024 + n) * 64 + dd0;
        dst[qb     ] = __float2bfloat16(z0);
        dst[qb + 16] = __float2bfloat16(z1);
        dst[qb + 32] = __float2bfloat16(z2);
        dst[qb + 48] = __float2bfloat16(z3);
      }
    }
  }
}

// ---------------------------------------------------------------------------
// MFMA flash attention. Block = (q-tile of 64, bh). 4 waves; wave owns 16
// q-rows. All LDS tiles XOR-swizzled; fragment reads at bank floor.
// ---------------------------------------------------------------------------
__global__ __launch_bounds__(256) void attn_mfma(
    const bf16* __restrict__ Qp, const bf16* __restrict__ Kp,
    const bf16* __restrict__ Vtb, bf16* __restrict__ ao)
{
  __shared__ __align__(16) bf16 Qs[64*64];
  __shared__ __align__(16) bf16 Ks[64*64];
  __shared__ __align__(16) bf16 Vs[64*64];   // V^T tile: rows=d, cols=kk
  __shared__ __align__(16) bf16 Ps[64*64];   // P, per-wave 16-row regions
  const int tid = threadIdx.x;
  const int l   = tid & 63;
  const int w   = tid >> 6;
  const int qt  = blockIdx.x;                // 0..15
  const int bh  = blockIdx.y;                // chunk-local b*12 + h
  const size_t base = (size_t)bh * 65536;

  #pragma unroll
  for (int i = 0; i < 2; i++) {
    const int idx = tid + i*256;
    const int row = idx >> 3, ch = idx & 7;
    const int slot = ch ^ (row & 7);
    *(uint4*)&Qs[row*64 + slot*8] =
        *(const uint4*)(Qp + base + (size_t)(qt*64 + row)*64 + ch*8);
  }
  __syncthreads();

  bf16x8 af[2];
  {
    const int row = w*16 + (l & 15);
    #pragma unroll
    for (int s = 0; s < 2; s++) {
      const int ch = (s*4 + (l >> 4)) ^ (row & 7);
      af[s] = *(const bf16x8*)&Qs[row*64 + ch*8];
    }
  }

  float m_i[4], l_i[4];
  #pragma unroll
  for (int v = 0; v < 4; v++) { m_i[v] = -3.0e38f; l_i[v] = 0.f; }
  f32x4 o[4] = {};

  for (int kt = 0; kt < 16; kt++) {
    __syncthreads();
    #pragma unroll
    for (int i = 0; i < 2; i++) {
      const int idx = tid + i*256;
      const int row = idx >> 3, ch = idx & 7;
      const int slot = ch ^ (row & 7);
      *(uint4*)&Ks[row*64 + slot*8] =
          *(const uint4*)(Kp + base + (size_t)(kt*64 + row)*64 + ch*8);
      *(uint4*)&Vs[row*64 + slot*8] =
          *(const uint4*)(Vtb + base + (size_t)row*1024 + kt*64 + ch*8);
    }
    __syncthreads();

    f32x4 s[4];
    #pragma unroll
    for (int nt = 0; nt < 4; nt++) {
      f32x4 a = {};
      const int nrow = nt*16 + (l & 15);
      #pragma unroll
      for (int ss = 0; ss < 2; ss++) {
        const int ch = (ss*4 + (l >> 4)) ^ (nrow & 7);
        bf16x8 bg = *(const bf16x8*)&Ks[nrow*64 + ch*8];
        a = __builtin_amdgcn_mfma_f32_16x16x32_bf16(af[ss], bg, a, 0, 0, 0);
      }
      s[nt] = a;
    }

    #pragma unroll
    for (int v = 0; v < 4; v++) {
      float m0 = fmaxf(fmaxf(s[0][v], s[1][v]), fmaxf(s[2][v], s[3][v]));
      #pragma unroll
      for (int off = 1; off < 16; off <<= 1)
        m0 = fmaxf(m0, __shfl_xor(m0, off));
      const float mx = fmaxf(m_i[v], m0);
      const float alpha = exp2f((m_i[v] - mx) * 1.4426950408889634f);
      m_i[v] = mx;
      float r = 0.f;
      #pragma unroll
      for (int nt = 0; nt < 4; nt++) {
        const float p = exp2f((s[nt][v] - mx) * 1.4426950408889634f);
        s[nt][v] = p;
        r += p;
      }
      #pragma unroll
      for (int off = 1; off < 16; off <<= 1)
        r += __shfl_xor(r, off);
      l_i[v] = l_i[v] * alpha + r;
      #pragma unroll
      for (int nt = 0; nt < 4; nt++) o[nt][v] *= alpha;
    }

    #pragma unroll
    for (int nt = 0; nt < 4; nt++) {
      const int kk = nt*16 + (l & 15);
      #pragma unroll
      for (int v = 0; v < 4; v++) {
        const int row = w*16 + (l >> 4)*4 + v;
        const int ch  = (kk >> 3) ^ (row & 7);
        Ps[row*64 + ch*8 + (kk & 7)] = __float2bfloat16(s[nt][v]);
      }
    }

    #pragma unroll
    for (int ss = 0; ss < 2; ss++) {
      const int prow = w*16 + (l & 15);
      const int pch  = (ss*4 + (l >> 4)) ^ (prow & 7);
      bf16x8 pa = *(const bf16x8*)&Ps[prow*64 + pch*8];
      #pragma unroll
      for (int ntd = 0; ntd < 4; ntd++) {
        const int drow = ntd*16 + (l & 15);
        const int vch  = (ss*4 + (l >> 4)) ^ (drow & 7);
        bf16x8 vb = *(const bf16x8*)&Vs[drow*64 + vch*8];
        o[ntd] = __builtin_amdgcn_mfma_f32_16x16x32_bf16(pa, vb, o[ntd], 0,0,0);
      }
    }
  }

  const int b = bh / 12, h = bh - b*12;
  #pragma unroll
  for (int v = 0; v < 4; v++) {
    const int r = qt*64 + w*16 + (l >> 4)*4 + v;
    const float inv = 1.0f / l_i[v];
    const size_t rowbase = ((size_t)(b*1024 + r)) * 768 + h*64;
    #pragma unroll
    for (int ntd = 0; ntd < 4; ntd++)
      ao[rowbase + ntd*16 + (l & 15)] = __float2bfloat16(o[ntd][v] * inv);
  }
}

// ---------------------------------------------------------------------------
// Plain MFMA NT-GEMM + bias (proj). Unchanged (verified).
// ---------------------------------------------------------------------------
__global__ __launch_bounds__(256) void gemm_mfma(
    const bf16* __restrict__ Ab, const bf16* __restrict__ WT,
    const void* __restrict__ bias, void* __restrict__ Cout,
    const int Nd, const int K, const int c_row_off,
    const int* __restrict__ flag, const int bias_mode, const int c_mode)
{
  const int fl = *flag;
  const bool bbf = (bias_mode == 2) ? (fl != 0) : (bias_mode != 0);
  const bool cbf = (c_mode == 2) ? (fl != 0) : (c_mode != 0);

  __shared__ __align__(16) unsigned short As[128*64];
  __shared__ __align__(16) unsigned short Bs[128*64];

  const int tid = threadIdx.x;
  const int l   = tid & 63;
  const int w   = tid >> 6;
  const int wm  = (w & 1) * 64;
  const int wn  = (w >> 1) * 64;
  const int row0 = blockIdx.x * 128;
  const int col0 = blockIdx.y * 128;

  const int trow  = tid >> 3;
  const int tch   = tid & 7;
  const int slotj = tch ^ (trow & 7);
  const bf16* Aptr = Ab + (size_t)(row0 + trow) * K + tch * 8;
  const bf16* Bptr = WT + (size_t)(col0 + trow) * K + tch * 8;
  const int lA = trow * 64 + slotj * 8;

  f32x4 acc[4][4] = {};

  for (int k0 = 0; k0 < K; k0 += 64) {
    uint4 av[4], bv[4];
    #pragma unroll
    for (int i = 0; i < 4; i++) {
      av[i] = *(const uint4*)(Aptr + (size_t)i*32*K + k0);
      bv[i] = *(const uint4*)(Bptr + (size_t)i*32*K + k0);
    }
    __syncthreads();
    #pragma unroll
    for (int i = 0; i < 4; i++) {
      *(uint4*)&As[lA + i*2048] = av[i];
      *(uint4*)&Bs[lA + i*2048] = bv[i];
    }
    __syncthreads();
    #pragma unroll
    for (int s = 0; s < 2; s++) {
      bf16x8 af[4], bg[4];
      const int ch = (s*4 + (l >> 4)) ^ (l & 7);
      #pragma unroll
      for (int i = 0; i < 4; i++) {
        const int rowm = wm + i*16 + (l & 15);
        const int rown = wn + i*16 + (l & 15);
        af[i] = *(const bf16x8*)&As[rowm*64 + ch*8];
        bg[i] = *(const bf16x8*)&Bs[rown*64 + ch*8];
      }
      #pragma unroll
      for (int i = 0; i < 4; i++)
        #pragma unroll
        for (int j = 0; j < 4; j++)
          acc[i][j] = __builtin_amdgcn_mfma_f32_16x16x32_bf16(
                          af[i], bg[j], acc[i][j], 0, 0, 0);
    }
  }

  const int cn    = col0 + wn + (l & 15);
  const int rbase = c_row_off + row0 + wm + (l >> 4) * 4;
  #pragma unroll
  for (int j = 0; j < 4; j++) {
    const int col = cn + j*16;
    const float bval = bbf ? tof(((const bf16*)bias)[col])
                           : ((const float*)bias)[col];
    #pragma unroll
    for (int i = 0; i < 4; i++) {
      #pragma unroll
      for (int v = 0; v < 4; v++) {
        const size_t r = (size_t)(rbase + i*16 + v);
        const float val = acc[i][j][v] + bval;
        if (cbf) ((bf16*)Cout)[r * Nd + col] = __float2bfloat16(val);
        else     ((float*)Cout)[r * Nd + col] = val;
      }
    }
  }
}

// ---------------------------------------------------------------------------
// ws: flag(256B) | WqkvT 3.54MB | WprojT 1.18MB |
//     xb | Qp | Kp | Vt | ao  (each CB*1.57MB)
// ---------------------------------------------------------------------------
extern "C" void kernel_launch(void* const* d_in, const int* in_sizes, int n_in,
                              void* d_out, int out_size, void* d_ws, size_t ws_size,
                              hipStream_t stream)
{
  (void)in_sizes; (void)n_in; (void)out_size;
  const void* x     = d_in[0];
  const void* Wqkv  = d_in[1];
  const void* bqkv  = d_in[2];
  const void* Wproj = d_in[3];
  const void* bproj = d_in[4];
  const int*  pos_h = (const int*)d_in[5];
  const int*  pos_w = (const int*)d_in[6];

  int* flag = (int*)d_ws;
  char* p = (char*)d_ws + 256;
  bf16* WqkvT  = (bf16*)p; p += (size_t)QC_ * C_ * 2;
  bf16* WprojT = (bf16*)p; p += (size_t)C_ * C_ * 2;

  const size_t fixed = 256 + (size_t)QC_*C_*2 + (size_t)C_*C_*2;
  const size_t perb  = 5 * (size_t)N_ * C_ * 2;   // xb,Qp,Kp,Vt,ao
  int CB = 4;
  if (ws_size < fixed + 4*perb) CB = 2;
  if (ws_size < fixed + 2*perb) CB = 1;
  const int Mc = CB * N_;
  const size_t tsz = (size_t)Mc * C_;

  bf16* xb  = (bf16*)p;
  bf16* Qp  = xb  + tsz;
  bf16* Kp  = Qp  + tsz;
  bf16* Vtb = Kp  + tsz;
  bf16* ao  = Vtb + tsz;

  detect_dtype<<<1, 256, 0, stream>>>((const unsigned*)x, flag);
  wt_cvt<<<dim3(QC_/32, C_/32), 256, 0, stream>>>(Wqkv, WqkvT, C_, QC_, flag);
  wt_cvt<<<dim3(C_/32,  C_/32), 256, 0, stream>>>(Wproj, WprojT, C_, C_, flag);

  for (int c0 = 0; c0 < B_; c0 += CB) {
    const int n4 = Mc * C_ / 4;
    cvt_x<<<(n4 + 255)/256, 256, 0, stream>>>(x, xb, flag, n4, c0 * N_ * C_ / 4);
    gemm_qkv_rope<<<dim3(Mc/128, QC_/128), 256, 0, stream>>>(
        xb, WqkvT, bqkv, Qp, Kp, Vtb, flag,
        pos_h + (size_t)c0*N_, pos_w + (size_t)c0*N_);
    attn_mfma<<<dim3(N_/64, CB*H_), 256, 0, stream>>>(Qp, Kp, Vtb, ao);
    gemm_mfma<<<dim3(Mc/128, C_/128), 256, 0, stream>>>(
        ao, WprojT, bproj, d_out, C_, C_, c0*N_, flag, 2, 2);
  }
}